// Round 1
// baseline (286.148 us; speedup 1.0000x reference)
//
#include <hip/hip_runtime.h>

typedef unsigned short u16;
typedef __attribute__((ext_vector_type(8))) short short8;
typedef __attribute__((ext_vector_type(4))) float f32x4;

// ---- helpers ----------------------------------------------------------

__device__ __forceinline__ u16 f2b(float f) {
  unsigned u = __float_as_uint(f);
  u = (u + 0x7FFFu + ((u >> 16) & 1u)) >> 16;  // RNE
  return (u16)u;
}

__device__ __forceinline__ void gload16(const void* g, void* l) {
  // async global->LDS, 16B per lane; LDS dest = wave-uniform base + lane*16
  __builtin_amdgcn_global_load_lds(
      (const __attribute__((address_space(1))) void*)g,
      (__attribute__((address_space(3))) void*)l, 16, 0, 0);
}

// ---- fp32 -> bf16 bulk convert ----------------------------------------

__global__ __launch_bounds__(256) void f2bf_kernel(const float* __restrict__ in,
                                                   u16* __restrict__ out, int n) {
  int i = (blockIdx.x * 256 + threadIdx.x) * 4;
  if (i >= n) return;
  float4 v = *(const float4*)(in + i);
  unsigned p0 = (unsigned)f2b(v.x) | ((unsigned)f2b(v.y) << 16);
  unsigned p1 = (unsigned)f2b(v.z) | ((unsigned)f2b(v.w) << 16);
  *(uint2*)(out + i) = make_uint2(p0, p1);
}

// ---- bf16 transpose: V[4096][1024] -> Vt[1024][4096] -------------------

__global__ __launch_bounds__(256) void transpose_kernel(const u16* __restrict__ V,
                                                        u16* __restrict__ Vt) {
  __shared__ u16 t[32][33];
  int bx = blockIdx.x;  // col tile (1024/32)
  int by = blockIdx.y;  // row tile (4096/32)
  int c = threadIdx.x & 31, r4 = threadIdx.x >> 5;  // r4 in 0..7
#pragma unroll
  for (int i = 0; i < 4; ++i) {
    int row = r4 * 4 + i;
    t[row][c] = V[(size_t)(by * 32 + row) * 1024 + bx * 32 + c];
  }
  __syncthreads();
#pragma unroll
  for (int i = 0; i < 4; ++i) {
    int row = r4 * 4 + i;  // col of V -> row of Vt (within tile)
    Vt[(size_t)(bx * 32 + row) * 4096 + by * 32 + c] = t[c][row];
  }
}

// ---- GEMM: C[4096][1024] = A[4096][1024] @ B[1024][1024]^T (bf16) ------
// 128x128 tile, BK=32, 4 waves (2x2), 16x16x32 bf16 MFMA, global_load_lds.

__device__ __forceinline__ void storeC(u16* C, size_t idx, float v) { C[idx] = f2b(v); }
__device__ __forceinline__ void storeC(float* C, size_t idx, float v) { C[idx] = v; }

template <typename OutT>
__device__ __forceinline__ void gemm_body(const u16* __restrict__ A,
                                          const u16* __restrict__ B,
                                          OutT* __restrict__ C) {
  __shared__ __align__(16) u16 lA[128 * 32];
  __shared__ __align__(16) u16 lB[128 * 32];
  const int tid = threadIdx.x;
  const int w = tid >> 6, lane = tid & 63, g = lane >> 4, lr = lane & 15;
  const int wr = w >> 1, wc = w & 1;
  const int m0 = blockIdx.y * 128, n0 = blockIdx.x * 128;

  f32x4 acc[4][4] = {};

  for (int k0 = 0; k0 < 1024; k0 += 32) {
#pragma unroll
    for (int j = 0; j < 2; ++j) {
      int c = tid + j * 256;           // 16B chunk id; row = c>>2, koff = (c&3)*8
      gload16(A + (size_t)(m0 + (c >> 2)) * 1024 + k0 + (c & 3) * 8,
              &lA[(j * 256 + w * 64) * 8]);
      gload16(B + (size_t)(n0 + (c >> 2)) * 1024 + k0 + (c & 3) * 8,
              &lB[(j * 256 + w * 64) * 8]);
    }
    __syncthreads();

    short8 af[4], bf[4];
#pragma unroll
    for (int i = 0; i < 4; ++i) {
      af[i] = *(const short8*)&lA[(wr * 64 + i * 16 + lr) * 32 + g * 8];
      bf[i] = *(const short8*)&lB[(wc * 64 + i * 16 + lr) * 32 + g * 8];
    }
#pragma unroll
    for (int mi = 0; mi < 4; ++mi)
#pragma unroll
      for (int ni = 0; ni < 4; ++ni)
        acc[mi][ni] =
            __builtin_amdgcn_mfma_f32_16x16x32_bf16(af[mi], bf[ni], acc[mi][ni], 0, 0, 0);
    __syncthreads();
  }

#pragma unroll
  for (int mi = 0; mi < 4; ++mi)
#pragma unroll
    for (int ni = 0; ni < 4; ++ni)
#pragma unroll
      for (int r = 0; r < 4; ++r) {
        size_t row = (size_t)(m0 + wr * 64 + mi * 16 + g * 4 + r);
        size_t col = (size_t)(n0 + wc * 64 + ni * 16 + lr);
        storeC(C, row * 1024 + col, acc[mi][ni][r]);
      }
}

__global__ __launch_bounds__(256) void gemm_qkv_kernel(
    const u16* __restrict__ A, const u16* __restrict__ W0, const u16* __restrict__ W1,
    const u16* __restrict__ W2, u16* __restrict__ C0, u16* __restrict__ C1,
    u16* __restrict__ C2) {
  int z = blockIdx.z;
  const u16* B = (z == 0) ? W0 : (z == 1) ? W1 : W2;
  u16* C = (z == 0) ? C0 : (z == 1) ? C1 : C2;
  gemm_body<u16>(A, B, C);
}

__global__ __launch_bounds__(256) void gemm_out_kernel(const u16* __restrict__ A,
                                                       const u16* __restrict__ B,
                                                       float* __restrict__ C) {
  gemm_body<float>(A, B, C);
}

// ---- flash attention (causal), bf16, 16x16x32 MFMA ---------------------
// block: 1 head x 64 Q-rows, 4 waves (16 rows each). K/Vt tiles of 64 keys
// staged swizzled; P relayout via per-wave LDS round-trip.

__global__ __launch_bounds__(256) void attn_kernel(const u16* __restrict__ Qg,
                                                   const u16* __restrict__ Kg,
                                                   const u16* __restrict__ Vtg,
                                                   u16* __restrict__ Og) {
  __shared__ __align__(16) u16 lK[64 * 64];
  __shared__ __align__(16) u16 lV[64 * 64];
  __shared__ __align__(16) u16 lP[4 * 16 * 64];
  const int tid = threadIdx.x;
  const int w = tid >> 6, lane = tid & 63, g = lane >> 4, lr = lane & 15;
  const int h = blockIdx.y;
  const int qb = (int)gridDim.x - 1 - (int)blockIdx.x;  // heavy tiles first

  short8 qa[2];
  {
    int qrow = qb * 64 + w * 16 + lr;  // A-frag row = lr
    const u16* qp = Qg + (size_t)qrow * 1024 + h * 64;
    qa[0] = *(const short8*)(qp + g * 8);
    qa[1] = *(const short8*)(qp + 32 + g * 8);
  }

  float m[4], lsum[4];
  f32x4 o[4] = {};
#pragma unroll
  for (int r = 0; r < 4; ++r) { m[r] = -1e30f; lsum[r] = 0.f; }

  u16* lPw = lP + w * 1024;  // 2KB per wave

  for (int kt = 0; kt <= qb; ++kt) {
    // stage K[64 keys][64 d] and Vt[64 d][64 keys], source pre-swizzled
#pragma unroll
    for (int j = 0; j < 2; ++j) {
      int c = tid + j * 256;
      int rr = c >> 3;
      int soff = ((c & 7) * 16) ^ ((rr & 7) << 4);
      gload16((const char*)(Kg + (size_t)(kt * 64 + rr) * 1024 + h * 64) + soff,
              (char*)lK + (j * 256 + w * 64) * 16);
      gload16((const char*)(Vtg + (size_t)(h * 64 + rr) * 4096 + kt * 64) + soff,
              (char*)lV + (j * 256 + w * 64) * 16);
    }
    __syncthreads();

    // S = Q K^T  (per wave: 16 rows x 64 keys)
    f32x4 s[4] = {};
#pragma unroll
    for (int nt = 0; nt < 4; ++nt) {
      int keyl = nt * 16 + lr;
      const char* rowp = (const char*)lK + keyl * 128;
      int swz = (keyl & 7) << 4;
#pragma unroll
      for (int kc = 0; kc < 2; ++kc) {
        short8 kb = *(const short8*)(rowp + ((g * 16 + kc * 64) ^ swz));
        s[nt] = __builtin_amdgcn_mfma_f32_16x16x32_bf16(qa[kc], kb, s[nt], 0, 0, 0);
      }
    }

    // scale + causal mask (diagonal tile only)
    const bool dia = (kt == qb);
#pragma unroll
    for (int nt = 0; nt < 4; ++nt) {
      int keyl = nt * 16 + lr;
#pragma unroll
      for (int r = 0; r < 4; ++r) {
        float xv = s[nt][r] * 0.125f;
        if (dia && keyl > w * 16 + g * 4 + r) xv = -1e30f;
        s[nt][r] = xv;
      }
    }

    // online softmax (rows live on 16-lane groups: row = 4g+r)
    float alpha[4];
#pragma unroll
    for (int r = 0; r < 4; ++r) {
      float v = fmaxf(fmaxf(s[0][r], s[1][r]), fmaxf(s[2][r], s[3][r]));
#pragma unroll
      for (int msk = 1; msk < 16; msk <<= 1) v = fmaxf(v, __shfl_xor(v, msk, 64));
      float mn = fmaxf(m[r], v);
      alpha[r] = __expf(m[r] - mn);
      m[r] = mn;
    }
#pragma unroll
    for (int r = 0; r < 4; ++r) {
      float sum = 0.f;
#pragma unroll
      for (int nt = 0; nt < 4; ++nt) {
        float p = __expf(s[nt][r] - m[r]);
        s[nt][r] = p;
        sum += p;
      }
#pragma unroll
      for (int msk = 1; msk < 16; msk <<= 1) sum += __shfl_xor(sum, msk, 64);
      lsum[r] = lsum[r] * alpha[r] + sum;
    }

    // P (C-layout) -> LDS bf16, swizzled rows of 128B
#pragma unroll
    for (int nt = 0; nt < 4; ++nt) {
      int keyl = nt * 16 + lr;
#pragma unroll
      for (int r = 0; r < 4; ++r) {
        int prow = g * 4 + r;
        *(u16*)((char*)lPw + prow * 128 + ((keyl * 2) ^ ((prow & 7) << 4))) =
            f2b(s[nt][r]);
      }
    }
    asm volatile("s_waitcnt lgkmcnt(0)" ::: "memory");

    // rescale O
#pragma unroll
    for (int nt = 0; nt < 4; ++nt)
#pragma unroll
      for (int r = 0; r < 4; ++r) o[nt][r] *= alpha[r];

    // O += P V   (A-frag: row=lr, keys 8g.. ; B-frag from Vt)
    short8 pa[2];
    {
      const char* prp = (const char*)lPw + lr * 128;
      int swz = (lr & 7) << 4;
      pa[0] = *(const short8*)(prp + ((g * 16) ^ swz));
      pa[1] = *(const short8*)(prp + ((g * 16 + 64) ^ swz));
    }
#pragma unroll
    for (int nt = 0; nt < 4; ++nt) {
      int d = nt * 16 + lr;
      const char* rowp = (const char*)lV + d * 128;
      int swz = (d & 7) << 4;
#pragma unroll
      for (int kc = 0; kc < 2; ++kc) {
        short8 vb = *(const short8*)(rowp + ((g * 16 + kc * 64) ^ swz));
        o[nt] = __builtin_amdgcn_mfma_f32_16x16x32_bf16(pa[kc], vb, o[nt], 0, 0, 0);
      }
    }
    __syncthreads();
  }

  // O /= lsum, write bf16
#pragma unroll
  for (int r = 0; r < 4; ++r) {
    float inv = 1.0f / lsum[r];
    size_t orow = (size_t)(qb * 64 + w * 16 + g * 4 + r);
#pragma unroll
    for (int nt = 0; nt < 4; ++nt)
      Og[orow * 1024 + h * 64 + nt * 16 + lr] = f2b(o[nt][r] * inv);
  }
}

// ---- launcher ----------------------------------------------------------

extern "C" void kernel_launch(void* const* d_in, const int* in_sizes, int n_in,
                              void* d_out, int out_size, void* d_ws, size_t ws_size,
                              hipStream_t stream) {
  const float* x = (const float*)d_in[0];
  const float* Wq = (const float*)d_in[1];
  const float* Wk = (const float*)d_in[2];
  const float* Wv = (const float*)d_in[3];
  const float* Wo = (const float*)d_in[4];
  float* out = (float*)d_out;
  char* ws = (char*)d_ws;
  const size_t MB = 1024 * 1024;

  u16* xb  = (u16*)(ws);            // 8MB; reused as attn-out after QKV GEMMs
  u16* wqb = (u16*)(ws + 8 * MB);   // 2MB
  u16* wkb = (u16*)(ws + 10 * MB);
  u16* wvb = (u16*)(ws + 12 * MB);
  u16* wob = (u16*)(ws + 14 * MB);
  u16* Qb  = (u16*)(ws + 16 * MB);  // 8MB each
  u16* Kb  = (u16*)(ws + 24 * MB);
  u16* Vb  = (u16*)(ws + 32 * MB);
  u16* Vtb = (u16*)(ws + 40 * MB);
  u16* att = xb;

  f2bf_kernel<<<4096, 256, 0, stream>>>(x, xb, 4096 * 1024);
  f2bf_kernel<<<1024, 256, 0, stream>>>(Wq, wqb, 1024 * 1024);
  f2bf_kernel<<<1024, 256, 0, stream>>>(Wk, wkb, 1024 * 1024);
  f2bf_kernel<<<1024, 256, 0, stream>>>(Wv, wvb, 1024 * 1024);
  f2bf_kernel<<<1024, 256, 0, stream>>>(Wo, wob, 1024 * 1024);

  gemm_qkv_kernel<<<dim3(8, 32, 3), 256, 0, stream>>>(xb, wqb, wkb, wvb, Qb, Kb, Vb);
  transpose_kernel<<<dim3(32, 128), 256, 0, stream>>>(Vb, Vtb);
  attn_kernel<<<dim3(64, 16), 256, 0, stream>>>(Qb, Kb, Vtb, att);
  gemm_out_kernel<<<dim3(8, 32), 256, 0, stream>>>(att, wob, out);
}

// Round 3
// 202.925 us; speedup vs baseline: 1.4101x; 1.4101x over previous
//
#include <hip/hip_runtime.h>

typedef unsigned short u16;
typedef unsigned int u32;
typedef __attribute__((ext_vector_type(8))) short short8;
typedef __attribute__((ext_vector_type(4))) float f32x4;
typedef __attribute__((ext_vector_type(16))) float f32x16;
typedef __attribute__((ext_vector_type(4))) u32 u32x4;

// ---- helpers ----------------------------------------------------------

__device__ __forceinline__ u16 f2b(float f) {
  unsigned u = __float_as_uint(f);
  u = (u + 0x7FFFu + ((u >> 16) & 1u)) >> 16;  // RNE
  return (u16)u;
}

__device__ __forceinline__ void gload16(const void* g, void* l) {
  __builtin_amdgcn_global_load_lds(
      (const __attribute__((address_space(1))) void*)g,
      (__attribute__((address_space(3))) void*)l, 16, 0, 0);
}

// ---- fp32 -> bf16 bulk convert (optional scale fold) -------------------

__global__ __launch_bounds__(256) void f2bf_kernel(const float* __restrict__ in,
                                                   u16* __restrict__ out, int n,
                                                   float scale) {
  int i = (blockIdx.x * 256 + threadIdx.x) * 4;
  if (i >= n) return;
  float4 v = *(const float4*)(in + i);
  unsigned p0 = (unsigned)f2b(v.x * scale) | ((unsigned)f2b(v.y * scale) << 16);
  unsigned p1 = (unsigned)f2b(v.z * scale) | ((unsigned)f2b(v.w * scale) << 16);
  *(uint2*)(out + i) = make_uint2(p0, p1);
}

// ---- bf16 transpose: V[4096][1024] -> Vt[1024][4096] -------------------

__global__ __launch_bounds__(256) void transpose_kernel(const u16* __restrict__ V,
                                                        u16* __restrict__ Vt) {
  __shared__ u16 t[32][33];
  int bx = blockIdx.x;
  int by = blockIdx.y;
  int c = threadIdx.x & 31, r4 = threadIdx.x >> 5;
#pragma unroll
  for (int i = 0; i < 4; ++i) {
    int row = r4 * 4 + i;
    t[row][c] = V[(size_t)(by * 32 + row) * 1024 + bx * 32 + c];
  }
  __syncthreads();
#pragma unroll
  for (int i = 0; i < 4; ++i) {
    int row = r4 * 4 + i;
    Vt[(size_t)(bx * 32 + row) * 4096 + by * 32 + c] = t[c][row];
  }
}

// ---- GEMM: C[4096][1024] = A[4096][1024] @ B[1024][1024]^T (bf16) ------

__device__ __forceinline__ void storeC(u16* C, size_t idx, float v) { C[idx] = f2b(v); }
__device__ __forceinline__ void storeC(float* C, size_t idx, float v) { C[idx] = v; }

template <typename OutT>
__device__ __forceinline__ void gemm_body(const u16* __restrict__ A,
                                          const u16* __restrict__ B,
                                          OutT* __restrict__ C) {
  __shared__ __align__(16) u16 lA[128 * 32];
  __shared__ __align__(16) u16 lB[128 * 32];
  const int tid = threadIdx.x;
  const int w = tid >> 6, lane = tid & 63, g = lane >> 4, lr = lane & 15;
  const int wr = w >> 1, wc = w & 1;
  const int m0 = blockIdx.y * 128, n0 = blockIdx.x * 128;

  f32x4 acc[4][4] = {};

  for (int k0 = 0; k0 < 1024; k0 += 32) {
#pragma unroll
    for (int j = 0; j < 2; ++j) {
      int c = tid + j * 256;
      gload16(A + (size_t)(m0 + (c >> 2)) * 1024 + k0 + (c & 3) * 8,
              &lA[(j * 256 + w * 64) * 8]);
      gload16(B + (size_t)(n0 + (c >> 2)) * 1024 + k0 + (c & 3) * 8,
              &lB[(j * 256 + w * 64) * 8]);
    }
    __syncthreads();

    short8 af[4], bf[4];
#pragma unroll
    for (int i = 0; i < 4; ++i) {
      af[i] = *(const short8*)&lA[(wr * 64 + i * 16 + lr) * 32 + g * 8];
      bf[i] = *(const short8*)&lB[(wc * 64 + i * 16 + lr) * 32 + g * 8];
    }
#pragma unroll
    for (int mi = 0; mi < 4; ++mi)
#pragma unroll
      for (int ni = 0; ni < 4; ++ni)
        acc[mi][ni] =
            __builtin_amdgcn_mfma_f32_16x16x32_bf16(af[mi], bf[ni], acc[mi][ni], 0, 0, 0);
    __syncthreads();
  }

#pragma unroll
  for (int mi = 0; mi < 4; ++mi)
#pragma unroll
    for (int ni = 0; ni < 4; ++ni)
#pragma unroll
      for (int r = 0; r < 4; ++r) {
        size_t row = (size_t)(m0 + wr * 64 + mi * 16 + g * 4 + r);
        size_t col = (size_t)(n0 + wc * 64 + ni * 16 + lr);
        storeC(C, row * 1024 + col, acc[mi][ni][r]);
      }
}

__global__ __launch_bounds__(256) void gemm_qkv_kernel(
    const u16* __restrict__ A, const u16* __restrict__ W0, const u16* __restrict__ W1,
    const u16* __restrict__ W2, u16* __restrict__ C0, u16* __restrict__ C1,
    u16* __restrict__ C2) {
  int z = blockIdx.z;
  const u16* B = (z == 0) ? W0 : (z == 1) ? W1 : W2;
  u16* C = (z == 0) ? C0 : (z == 1) ? C1 : C2;
  gemm_body<u16>(A, B, C);
}

__global__ __launch_bounds__(256) void gemm_out_kernel(const u16* __restrict__ A,
                                                       const u16* __restrict__ B,
                                                       float* __restrict__ C) {
  gemm_body<float>(A, B, C);
}

// ---- flash attention, swapped-operand 32x32 structure ------------------
// 1 wave = 32 q rows of one head; 4 waves/block, 512 blocks.
// S^T = mfma(K, Q): col=query=lane&31, row=key=crow(r,hi)=(r&3)+8*(r>>2)+4*hi.
// O^T = mfma(V^T, P^T): col=query (lane-local normalization), row=d.
// Q pre-scaled by 0.125*log2e (folded into Wq) -> softmax in exp2 domain.
// No inline asm; masked logits use -30000 (exp2 -> exact 0, no 1e30 anywhere).

#define NEGINF (-30000.0f)

__global__ __launch_bounds__(256, 2) void attn_kernel(const u16* __restrict__ Qg,
                                                      const u16* __restrict__ Kg,
                                                      const u16* __restrict__ Vtg,
                                                      u16* __restrict__ Og) {
  __shared__ __align__(16) u16 lO[4][2048];
  const int tid = threadIdx.x, w = tid >> 6, lane = tid & 63;
  const int l31 = lane & 31, hi = lane >> 5;
  const int bid = blockIdx.x;
  const int h = bid & 15;                         // head
  const int ib = bid >> 4;                        // 0..31
  const int qt = (ib < 16) ? (31 - ib) : (ib - 16);  // heavy/light pairing
  const int qw = qt * 128 + w * 32;               // wave's first q row
  const int nt = (qw >> 6) + 1;                   // causal KV tiles of 64

  const u16* Qp = Qg + (size_t)(qw + l31) * 1024 + h * 64 + hi * 8;
  const u16* Kp = Kg + (size_t)l31 * 1024 + h * 64 + hi * 8;
  const u16* Vp = Vtg + (size_t)(h * 64 + l31) * 4096 + hi * 8;

  short8 qf[4];
#pragma unroll
  for (int kc = 0; kc < 4; ++kc) qf[kc] = *(const short8*)(Qp + kc * 16);

  short8 kf[2][4], vf[2][4];
#pragma unroll
  for (int kt2 = 0; kt2 < 2; ++kt2)
#pragma unroll
    for (int kc = 0; kc < 4; ++kc)
      kf[kt2][kc] = *(const short8*)(Kp + (size_t)kt2 * 32768 + kc * 16);
#pragma unroll
  for (int dt = 0; dt < 2; ++dt)
#pragma unroll
    for (int ks = 0; ks < 4; ++ks)
      vf[dt][ks] = *(const short8*)(Vp + (size_t)dt * 131072 + ks * 16);

  f32x16 ot[2] = {};
  float m = NEGINF, lsum = 0.f;

  for (int kt = 0; kt < nt; ++kt) {
    const int kbase = kt * 64;

    // S^T = K · Q^T  (8 mfma)
    f32x16 st[2] = {};
#pragma unroll
    for (int kt2 = 0; kt2 < 2; ++kt2)
#pragma unroll
      for (int kc = 0; kc < 4; ++kc)
        st[kt2] = __builtin_amdgcn_mfma_f32_32x32x16_bf16(kf[kt2][kc], qf[kc],
                                                          st[kt2], 0, 0, 0);

    if (kt + 1 < nt) {  // prefetch next K tile; overlaps softmax+PV
      const u16* Kn = Kp + (size_t)(kbase + 64) * 1024;
#pragma unroll
      for (int kt2 = 0; kt2 < 2; ++kt2)
#pragma unroll
        for (int kc = 0; kc < 4; ++kc)
          kf[kt2][kc] = *(const short8*)(Kn + (size_t)kt2 * 32768 + kc * 16);
    }

    if (kt == nt - 1) {  // causal mask, diagonal tile only
      const int q = qw + l31;
#pragma unroll
      for (int kt2 = 0; kt2 < 2; ++kt2)
#pragma unroll
        for (int r = 0; r < 16; ++r) {
          int key = kbase + kt2 * 32 + (r & 3) + 8 * (r >> 2) + 4 * hi;
          if (key > q) st[kt2][r] = NEGINF;
        }
    }

    // row max: in-lane + one cross-half exchange
    float pm = NEGINF;
#pragma unroll
    for (int kt2 = 0; kt2 < 2; ++kt2)
#pragma unroll
      for (int r = 0; r < 16; ++r) pm = fmaxf(pm, st[kt2][r]);
    pm = fmaxf(pm, __shfl_xor(pm, 32, 64));

    // always-rescale online softmax (log2 domain)
    {
      float mn = fmaxf(m, pm);
      float al = exp2f(m - mn);
      lsum *= al;
#pragma unroll
      for (int dt = 0; dt < 2; ++dt)
#pragma unroll
        for (int r = 0; r < 16; ++r) ot[dt][r] *= al;
      m = mn;
    }

    float ps = 0.f;
#pragma unroll
    for (int kt2 = 0; kt2 < 2; ++kt2)
#pragma unroll
      for (int r = 0; r < 16; ++r) {
        float p = exp2f(st[kt2][r] - m);
        st[kt2][r] = p;
        ps += p;
      }
    ps += __shfl_xor(ps, 32, 64);
    lsum += ps;

    // P -> bf16 B-fragments, pure-C pack (no asm)
    // pa[ks] element e must hold P^T[key = ks*16 + 8*hi + e][query l31]
    short8 pa[4];
#pragma unroll
    for (int ks = 0; ks < 4; ++ks) {
      const f32x16 P = st[ks >> 1];
      const int b = 8 * (ks & 1);
      // own keys: pk0/pk1 = crow(b+0..3) = {0,1,2,3}+4*hi (+8*(b/8)*? folded)
      // pk2/pk3 = crow(b+4..7) = {8,9,10,11}+4*hi
      u32 pk0 = (u32)f2b(P[b + 0]) | ((u32)f2b(P[b + 1]) << 16);
      u32 pk1 = (u32)f2b(P[b + 2]) | ((u32)f2b(P[b + 3]) << 16);
      u32 pk2 = (u32)f2b(P[b + 4]) | ((u32)f2b(P[b + 5]) << 16);
      u32 pk3 = (u32)f2b(P[b + 6]) | ((u32)f2b(P[b + 7]) << 16);
      u32 s0 = (u32)__shfl_xor((int)pk0, 32, 64);
      u32 s1 = (u32)__shfl_xor((int)pk1, 32, 64);
      u32 s2 = (u32)__shfl_xor((int)pk2, 32, 64);
      u32 s3 = (u32)__shfl_xor((int)pk3, 32, 64);
      u32x4 t;
      t.x = hi ? s2 : pk0;   // hi=0: keys {0,1};  hi=1: keys {8,9}
      t.y = hi ? s3 : pk1;   // hi=0: keys {2,3};  hi=1: keys {10,11}
      t.z = hi ? pk2 : s0;   // hi=0: keys {4,5};  hi=1: keys {12,13}
      t.w = hi ? pk3 : s1;   // hi=0: keys {6,7};  hi=1: keys {14,15}
      pa[ks] = __builtin_bit_cast(short8, t);
    }

    // O^T += V^T · P^T  (8 mfma)
#pragma unroll
    for (int dt = 0; dt < 2; ++dt)
#pragma unroll
      for (int ks = 0; ks < 4; ++ks)
        ot[dt] = __builtin_amdgcn_mfma_f32_32x32x16_bf16(vf[dt][ks], pa[ks],
                                                         ot[dt], 0, 0, 0);

    if (kt + 1 < nt) {  // prefetch next V tile
      const u16* Vn = Vp + kbase + 64;
#pragma unroll
      for (int dt = 0; dt < 2; ++dt)
#pragma unroll
        for (int ks = 0; ks < 4; ++ks)
          vf[dt][ks] = *(const short8*)(Vn + (size_t)dt * 131072 + ks * 16);
    }
  }

  // epilogue: normalize (lane-local), LDS transpose, coalesced store
  const float inv = 1.0f / lsum;
  char* pw = (char*)&lO[w][0];
#pragma unroll
  for (int dt = 0; dt < 2; ++dt)
#pragma unroll
    for (int r = 0; r < 16; ++r) {
      int d = dt * 32 + (r & 3) + 8 * (r >> 2) + 4 * hi;
      *(u16*)(pw + l31 * 128 + ((d * 2) ^ ((l31 & 7) << 4))) = f2b(ot[dt][r] * inv);
    }
  __syncthreads();
  const int row = lane >> 1;
#pragma unroll
  for (int ii = 0; ii < 4; ++ii) {
    int c = (lane & 1) * 4 + ii;
    short8 v = *(const short8*)(pw + row * 128 + ((c * 16) ^ ((row & 7) << 4)));
    *(short8*)(Og + (size_t)(qw + row) * 1024 + h * 64 + c * 8) = v;
  }
}

// ---- launcher ----------------------------------------------------------

extern "C" void kernel_launch(void* const* d_in, const int* in_sizes, int n_in,
                              void* d_out, int out_size, void* d_ws, size_t ws_size,
                              hipStream_t stream) {
  const float* x = (const float*)d_in[0];
  const float* Wq = (const float*)d_in[1];
  const float* Wk = (const float*)d_in[2];
  const float* Wv = (const float*)d_in[3];
  const float* Wo = (const float*)d_in[4];
  float* out = (float*)d_out;
  char* ws = (char*)d_ws;
  const size_t MB = 1024 * 1024;

  u16* xb  = (u16*)(ws);
  u16* wqb = (u16*)(ws + 8 * MB);
  u16* wkb = (u16*)(ws + 10 * MB);
  u16* wvb = (u16*)(ws + 12 * MB);
  u16* wob = (u16*)(ws + 14 * MB);
  u16* Qb  = (u16*)(ws + 16 * MB);
  u16* Kb  = (u16*)(ws + 24 * MB);
  u16* Vb  = (u16*)(ws + 32 * MB);
  u16* Vtb = (u16*)(ws + 40 * MB);
  u16* att = xb;

  // 0.125 = 1/sqrt(D); *log2(e) so softmax runs in exp2 domain
  const float qscale = 0.125f * 1.4426950408889634f;

  f2bf_kernel<<<4096, 256, 0, stream>>>(x, xb, 4096 * 1024, 1.f);
  f2bf_kernel<<<1024, 256, 0, stream>>>(Wq, wqb, 1024 * 1024, qscale);
  f2bf_kernel<<<1024, 256, 0, stream>>>(Wk, wkb, 1024 * 1024, 1.f);
  f2bf_kernel<<<1024, 256, 0, stream>>>(Wv, wvb, 1024 * 1024, 1.f);
  f2bf_kernel<<<1024, 256, 0, stream>>>(Wo, wob, 1024 * 1024, 1.f);

  gemm_qkv_kernel<<<dim3(8, 32, 3), 256, 0, stream>>>(xb, wqb, wkb, wvb, Qb, Kb, Vb);
  transpose_kernel<<<dim3(32, 128), 256, 0, stream>>>(Vb, Vtb);
  attn_kernel<<<512, 256, 0, stream>>>(Qb, Kb, Vtb, att);
  gemm_out_kernel<<<dim3(8, 32), 256, 0, stream>>>(att, wob, out);
}